// Round 17
// baseline (74.705 us; speedup 1.0000x reference)
//
#include <hip/hip_runtime.h>
#include <hip/hip_bf16.h>

// EventSpecificTimingHeads: E=16 per-event attention heads on shared features.
// Round 17: qkv widened to 128x128 tiles (grid 3x32x16; ct2=0 -> q, 1 -> k,
// 2 -> v-repack). 2x MFMA per staged byte, half the blocks/barriers, x
// re-reads halved. attn (r15 barrier-free) / head (r16) / convert unchanged.

#define E_ 16
#define B_ 8
#define S_ 512
#define D_ 128
#define H_ 4
#define DH_ 32
#define H2_ 64
#define M_ (B_ * S_)
// 1/sqrt(32) * log2(e): scores come out of QK^T in log2 domain.
#define QK_SCALE_L2E 0.25503472437616588f

#define ATTN_LDS_BYTES (512 * 80 + 32 * 1040)       // 74240
#define HEAD_LDS_BYTES (128 * 136 * 2 * 2)          // 69632
#define QKV_LDS_BYTES  (128 * 136 * 2 * 2)          // 69632 (>= rp 128*132*4)

typedef __attribute__((ext_vector_type(4))) short bf16x4;
typedef __attribute__((ext_vector_type(8))) short bf16x8;
typedef __attribute__((ext_vector_type(4))) float f32x4;

__device__ __forceinline__ short f2bf(float f) {
    unsigned u = __builtin_bit_cast(unsigned, f);
    u += 0x7fffu + ((u >> 16) & 1u);   // RNE
    return (short)(u >> 16);
}

__device__ __forceinline__ unsigned pk2(float lo, float hi) {
    __hip_bfloat162 t = __float22bfloat162_rn(make_float2(lo, hi));
    unsigned r;
    __builtin_memcpy(&r, &t, sizeof(r));
    return r;
}

__device__ __forceinline__ bf16x8 cat8(bf16x4 lo, bf16x4 hi) {
    return __builtin_shufflevector(lo, hi, 0, 1, 2, 3, 4, 5, 6, 7);
}

// ---------------------------------------------------------------------------
// Kernel 0: fp32 -> bf16 convert: x, Wqkv, Wo, W1. (convert once, read many)
// ---------------------------------------------------------------------------
__global__ __launch_bounds__(256) void convert_kernel(
    const float* __restrict__ x, const float* __restrict__ w,
    const float* __restrict__ wo, const float* __restrict__ w1,
    short* __restrict__ xbf, short* __restrict__ wbf,
    short* __restrict__ wobf, short* __restrict__ w1bf)
{
    const int XN  = (M_ * D_) / 8;             // 65536
    const int WN  = (E_ * 3 * D_ * D_) / 8;    // 98304
    const int WON = (E_ * D_ * D_) / 8;        // 32768
    const int W1N = (E_ * H2_ * D_) / 8;       // 16384
    int idx = blockIdx.x * 256 + threadIdx.x;
    const float* src; short* dst; int off;
    if (idx < XN)                        { src = x;  dst = xbf;  off = idx; }
    else if (idx < XN + WN)              { src = w;  dst = wbf;  off = idx - XN; }
    else if (idx < XN + WN + WON)        { src = wo; dst = wobf; off = idx - XN - WN; }
    else if (idx < XN + WN + WON + W1N)  { src = w1; dst = w1bf; off = idx - XN - WN - WON; }
    else return;
    float4 v0 = *(const float4*)&src[(size_t)off * 8];
    float4 v1 = *(const float4*)&src[(size_t)off * 8 + 4];
    bf16x8 o;
    o[0] = f2bf(v0.x); o[1] = f2bf(v0.y); o[2] = f2bf(v0.z); o[3] = f2bf(v0.w);
    o[4] = f2bf(v1.x); o[5] = f2bf(v1.y); o[6] = f2bf(v1.z); o[7] = f2bf(v1.w);
    *(bf16x8*)&dst[(size_t)off * 8] = o;
}

// ---------------------------------------------------------------------------
// Kernel 1: QKV GEMM, 512-thr blocks, 128(m) x 128(n) tiles, K=128.
// grid (ct2=0..2, rt=0..31, e). ct2: 0=q (scaled), 1=k, 2=v (repack).
// 8 waves: m0=(w>>2)*64, n0=(w&3)*32; per wave acc[4][2] (64m x 32n).
// ---------------------------------------------------------------------------
__global__ __launch_bounds__(512) void qkv_mfma_kernel(
    const short* __restrict__ xbf,   // [4096][128] bf16
    const short* __restrict__ wbf,   // [16][384][128] bf16
    const float* __restrict__ bqkv,  // [16][384]
    short* __restrict__ q, short* __restrict__ k, short* __restrict__ v)
{
    extern __shared__ __align__(16) char lds[];
    short (*xs)[136] = (short(*)[136])lds;
    short (*ws)[136] = (short(*)[136])(lds + 128 * 136 * 2);

    const int ct2 = blockIdx.x;  // 0..2
    const int rt  = blockIdx.y;  // 0..31 (128-row tiles)
    const int e   = blockIdx.z;  // 0..15
    const int tid = threadIdx.x;
    const int w    = tid >> 6;
    const int lane = tid & 63;
    const int l15  = lane & 15;
    const int g    = lane >> 4;

    // stage x tile 128x128 and W tile 128x128 (2048 chunks each)
    #pragma unroll
    for (int p = 0; p < 4; ++p) {
        int idx = tid + p * 512;
        int row = idx >> 4, c8 = (idx & 15) * 8;
        *(bf16x8*)&xs[row][c8] =
            *(const bf16x8*)&xbf[(size_t)(rt * 128 + row) * 128 + c8];
        *(bf16x8*)&ws[row][c8] =
            *(const bf16x8*)&wbf[((size_t)e * 384 + ct2 * 128 + row) * 128 + c8];
    }
    __syncthreads();

    const int m0 = (w >> 2) * 64;   // 0 or 64
    const int n0 = (w & 3) * 32;    // 0,32,64,96
    f32x4 acc[4][2] = {};

    #pragma unroll
    for (int kk = 0; kk < 128; kk += 32) {
        bf16x8 A0 = cat8(*(const bf16x4*)&ws[n0      + l15][kk + 4 * g],
                         *(const bf16x4*)&ws[n0      + l15][kk + 16 + 4 * g]);
        bf16x8 A1 = cat8(*(const bf16x4*)&ws[n0 + 16 + l15][kk + 4 * g],
                         *(const bf16x4*)&ws[n0 + 16 + l15][kk + 16 + 4 * g]);
        #pragma unroll
        for (int mm = 0; mm < 4; ++mm) {
            bf16x8 Bm = cat8(*(const bf16x4*)&xs[m0 + mm * 16 + l15][kk + 4 * g],
                             *(const bf16x4*)&xs[m0 + mm * 16 + l15][kk + 16 + 4 * g]);
            acc[mm][0] = __builtin_amdgcn_mfma_f32_16x16x32_bf16(A0, Bm, acc[mm][0], 0, 0, 0);
            acc[mm][1] = __builtin_amdgcn_mfma_f32_16x16x32_bf16(A1, Bm, acc[mm][1], 0, 0, 0);
        }
    }

    if (ct2 < 2) {
        short* dst = (ct2 == 0) ? q : k;
        const float scale = (ct2 == 0) ? QK_SCALE_L2E : 1.0f;
        #pragma unroll
        for (int mm = 0; mm < 4; ++mm) {
            #pragma unroll
            for (int nn = 0; nn < 2; ++nn) {
                const int d  = n0 + nn * 16 + 4 * g;        // 0..127 within q/k
                const int h  = d >> 5, dh = d & 31;
                const int jb = ct2 * 128 + d;               // bias col
                const float b0 = bqkv[e * 384 + jb + 0];
                const float b1 = bqkv[e * 384 + jb + 1];
                const float b2 = bqkv[e * 384 + jb + 2];
                const float b3 = bqkv[e * 384 + jb + 3];
                const int m  = rt * 128 + m0 + mm * 16 + l15;
                const int bb = m >> 9, s = m & 511;
                bf16x4 o;
                o[0] = f2bf((acc[mm][nn][0] + b0) * scale);
                o[1] = f2bf((acc[mm][nn][1] + b1) * scale);
                o[2] = f2bf((acc[mm][nn][2] + b2) * scale);
                o[3] = f2bf((acc[mm][nn][3] + b3) * scale);
                *(bf16x4*)&dst[((((size_t)e * B_ + bb) * H_ + h) * S_ + s) * DH_ + dh] = o;
            }
        }
    } else {
        // v: repack through LDS to transposed [dh][s] layout
        __syncthreads();
        float (*rp)[132] = (float(*)[132])lds;   // [128 ch][128 m + pad] 67.6 KB
        #pragma unroll
        for (int mm = 0; mm < 4; ++mm) {
            #pragma unroll
            for (int nn = 0; nn < 2; ++nn) {
                const int jl = n0 + nn * 16 + 4 * g;
                const int ml = m0 + mm * 16 + l15;
                rp[jl + 0][ml] = acc[mm][nn][0];
                rp[jl + 1][ml] = acc[mm][nn][1];
                rp[jl + 2][ml] = acc[mm][nn][2];
                rp[jl + 3][ml] = acc[mm][nn][3];
            }
        }
        __syncthreads();
        const int bb = (rt * 128) >> 9;
        const int sb = (rt * 128) & 511;
        #pragma unroll
        for (int p = 0; p < 4; ++p) {
            int task = tid + p * 512;          // 2048 tasks: 128 ch x 16 groups
            int jl = task >> 4, sc = (task & 15) * 8;
            const int h = jl >> 5, dh = jl & 31;
            const float bias = bqkv[e * 384 + 256 + jl];
            bf16x8 o;
            #pragma unroll
            for (int j = 0; j < 8; ++j) o[j] = f2bf(rp[jl][sc + j] + bias);
            *(bf16x8*)&v[((((size_t)e * B_ + bb) * H_ + h) * DH_ + dh) * S_ + sb + sc] = o;
        }
    }
}

// ---------------------------------------------------------------------------
// Kernel 2: flash attention, barrier-free (unchanged from r15).
// ---------------------------------------------------------------------------
__global__ __launch_bounds__(512) void attn_kernel(
    const short* __restrict__ q, const short* __restrict__ k,
    const short* __restrict__ vt, short* __restrict__ ctxbf)
{
    extern __shared__ __align__(16) char smem[];
    char* Kbase  = smem;            // [512 rows][80 B]
    char* VTbase = smem + 40960;    // [32 rows][1040 B]

    const int bh  = blockIdx.x;   // 0..31
    const int e   = blockIdx.y;   // 0..15
    const int tid = threadIdx.x;
    const int w    = tid >> 6;
    const int lane = tid & 63;
    const int l15  = lane & 15;
    const int g    = lane >> 4;

    const size_t base = ((size_t)e * 32 + bh) * (S_ * DH_);
    const short* qg = q  + base;
    const short* kg = k  + base;
    const short* vg = vt + base;

    {
        const uint4* src = (const uint4*)(kg + (size_t)tid * DH_);
        uint4* dst = (uint4*)(Kbase + (size_t)tid * 80);
        dst[0] = src[0]; dst[1] = src[1]; dst[2] = src[2]; dst[3] = src[3];
    }
    {
        int d = tid >> 4, c0 = (tid & 15) * 32;
        const uint4* src = (const uint4*)(vg + (size_t)d * S_ + c0);
        uint4* dst = (uint4*)(VTbase + (size_t)d * 1040 + c0 * 2);
        dst[0] = src[0]; dst[1] = src[1]; dst[2] = src[2]; dst[3] = src[3];
    }
    bf16x8 bq[4];
    #pragma unroll
    for (int qf = 0; qf < 4; ++qf) {
        const short* qp = qg + (size_t)(w * 64 + qf * 16 + l15) * DH_;
        bq[qf] = cat8(*(const bf16x4*)(qp + 4 * g),
                      *(const bf16x4*)(qp + 16 + 4 * g));
    }
    __syncthreads();   // the ONLY barrier

    f32x4 acc0[4] = {}, acc1[4] = {};
    float lsum[4] = {0.f, 0.f, 0.f, 0.f};

    for (int kt = 0; kt < 16; ++kt) {
        bf16x8 ka[2];
        #pragma unroll
        for (int tt = 0; tt < 2; ++tt) {
            const int row_l = (kt * 2 + tt) * 16 + l15;
            const char* kp = Kbase + (size_t)row_l * 80 + g * 8;
            ka[tt] = cat8(*(const bf16x4*)kp, *(const bf16x4*)(kp + 32));
        }
        const int keyb = kt * 32;
        const char* vp = VTbase + (size_t)l15 * 1040 + (keyb + 4 * g) * 2;
        bf16x8 va0 = cat8(*(const bf16x4*)vp, *(const bf16x4*)(vp + 32));
        const char* vp1 = vp + 16 * 1040;
        bf16x8 va1 = cat8(*(const bf16x4*)vp1, *(const bf16x4*)(vp1 + 32));

        #pragma unroll
        for (int qf = 0; qf < 4; ++qf) {
            f32x4 z = {0.f, 0.f, 0.f, 0.f};
            f32x4 s0 = __builtin_amdgcn_mfma_f32_16x16x32_bf16(ka[0], bq[qf], z, 0, 0, 0);
            f32x4 s1 = __builtin_amdgcn_mfma_f32_16x16x32_bf16(ka[1], bq[qf], z, 0, 0, 0);
            float p0 = __builtin_amdgcn_exp2f(s0[0]);
            float p1 = __builtin_amdgcn_exp2f(s0[1]);
            float p2 = __builtin_amdgcn_exp2f(s0[2]);
            float p3 = __builtin_amdgcn_exp2f(s0[3]);
            float p4 = __builtin_amdgcn_exp2f(s1[0]);
            float p5 = __builtin_amdgcn_exp2f(s1[1]);
            float p6 = __builtin_amdgcn_exp2f(s1[2]);
            float p7 = __builtin_amdgcn_exp2f(s1[3]);
            lsum[qf] += ((p0 + p1) + (p2 + p3)) + ((p4 + p5) + (p6 + p7));
            uint4 uu = make_uint4(pk2(p0, p1), pk2(p2, p3),
                                  pk2(p4, p5), pk2(p6, p7));
            bf16x8 pf = __builtin_bit_cast(bf16x8, uu);
            acc0[qf] = __builtin_amdgcn_mfma_f32_16x16x32_bf16(va0, pf, acc0[qf], 0, 0, 0);
            acc1[qf] = __builtin_amdgcn_mfma_f32_16x16x32_bf16(va1, pf, acc1[qf], 0, 0, 0);
        }
    }

    const int b = bh >> 2, h = bh & 3;
    #pragma unroll
    for (int qf = 0; qf < 4; ++qf) {
        float ls = lsum[qf];
        ls += __shfl_xor(ls, 16);
        ls += __shfl_xor(ls, 32);
        const float inv = 1.0f / ls;
        const int qrow = w * 64 + qf * 16 + l15;
        short* cg = ctxbf + (((size_t)(e * B_ + b) * S_ + qrow) * D_ + h * DH_);
        bf16x4 o0, o1;
        #pragma unroll
        for (int r = 0; r < 4; ++r) {
            o0[r] = f2bf(acc0[qf][r] * inv);
            o1[r] = f2bf(acc1[qf][r] * inv);
        }
        *(bf16x4*)&cg[4 * g]      = o0;
        *(bf16x4*)&cg[16 + 4 * g] = o1;
    }
}

// ---------------------------------------------------------------------------
// Kernel 3: head, 512-thr blocks, 128 rows (unchanged from r16).
// ---------------------------------------------------------------------------
__global__ __launch_bounds__(512) void head_mfma_kernel(
    const short* __restrict__ ctxbf,  // [E][4096][128] bf16
    const short* __restrict__ wobf,   // [E][128][128] bf16
    const float* __restrict__ bo,     // [E][128]
    const short* __restrict__ w1bf,   // [E][64][128] bf16
    const float* __restrict__ b1,     // [E][64]
    const float* __restrict__ W2,     // [E][64]
    const float* __restrict__ b2,     // [E]
    float* __restrict__ out)          // [B][S][E]
{
    extern __shared__ __align__(16) char smem[];
    short (*Wos)[136] = (short(*)[136])smem;
    short (*cts)[136] = (short(*)[136])(smem + 128 * 136 * 2);

    const int mt  = blockIdx.x;   // 0..31
    const int e   = blockIdx.y;
    const int tid = threadIdx.x;
    const int w    = tid >> 6;
    const int lane = tid & 63;
    const int l15  = lane & 15;
    const int g    = lane >> 4;

    #pragma unroll
    for (int p = 0; p < 4; ++p) {
        int idx = tid + p * 512;
        int row = idx >> 4, c8 = (idx & 15) * 8;
        *(bf16x8*)&Wos[row][c8] =
            *(const bf16x8*)&wobf[((size_t)e * 128 + row) * 128 + c8];
        *(bf16x8*)&cts[row][c8] =
            *(const bf16x8*)&ctxbf[((size_t)e * M_ + mt * 128 + row) * 128 + c8];
    }
    __syncthreads();

    f32x4 accA[8] = {};
    #pragma unroll
    for (int kk = 0; kk < 128; kk += 32) {
        bf16x8 a = cat8(*(const bf16x4*)&cts[w * 16 + l15][kk + 4 * g],
                        *(const bf16x4*)&cts[w * 16 + l15][kk + 16 + 4 * g]);
        #pragma unroll
        for (int t = 0; t < 8; ++t) {
            bf16x8 bfr = cat8(*(const bf16x4*)&Wos[t * 16 + l15][kk + 4 * g],
                              *(const bf16x4*)&Wos[t * 16 + l15][kk + 16 + 4 * g]);
            accA[t] = __builtin_amdgcn_mfma_f32_16x16x32_bf16(a, bfr, accA[t], 0, 0, 0);
        }
    }
    __syncthreads();

    #pragma unroll
    for (int p = 0; p < 2; ++p) {
        int idx = tid + p * 512;
        int row = idx >> 4, c8 = (idx & 15) * 8;
        *(bf16x8*)&Wos[row][c8] =
            *(const bf16x8*)&w1bf[((size_t)e * 64 + row) * 128 + c8];
    }
    #pragma unroll
    for (int t = 0; t < 8; ++t) {
        const float bov = bo[e * 128 + t * 16 + l15];
        #pragma unroll
        for (int r = 0; r < 4; ++r)
            cts[w * 16 + 4 * g + r][t * 16 + l15] = f2bf(accA[t][r] + bov);
    }
    __syncthreads();

    f32x4 accB[4] = {};
    #pragma unroll
    for (int kk = 0; kk < 128; kk += 32) {
        bf16x8 a = cat8(*(const bf16x4*)&cts[w * 16 + l15][kk + 4 * g],
                        *(const bf16x4*)&cts[w * 16 + l15][kk + 16 + 4 * g]);
        #pragma unroll
        for (int t = 0; t < 4; ++t) {
            bf16x8 bfr = cat8(*(const bf16x4*)&Wos[t * 16 + l15][kk + 4 * g],
                              *(const bf16x4*)&Wos[t * 16 + l15][kk + 16 + 4 * g]);
            accB[t] = __builtin_amdgcn_mfma_f32_16x16x32_bf16(a, bfr, accB[t], 0, 0, 0);
        }
    }

    float b1v[4], w2v[4];
    #pragma unroll
    for (int t = 0; t < 4; ++t) {
        b1v[t] = b1[e * 64 + t * 16 + l15];
        w2v[t] = W2[e * 64 + t * 16 + l15];
    }
    const float b2v = b2[e];
    #pragma unroll
    for (int r = 0; r < 4; ++r) {
        float s = 0.f;
        #pragma unroll
        for (int t = 0; t < 4; ++t)
            s += fmaxf(accB[t][r] + b1v[t], 0.f) * w2v[t];
        s += __shfl_xor(s, 1);
        s += __shfl_xor(s, 2);
        s += __shfl_xor(s, 4);
        s += __shfl_xor(s, 8);
        if (l15 == 0) {
            const int m = mt * 128 + w * 16 + 4 * g + r;
            const int bb = m >> 9, ss = m & 511;
            out[((size_t)(bb * S_ + ss)) * E_ + e] = s + b2v;
        }
    }
}

// ---------------------------------------------------------------------------
extern "C" void kernel_launch(void* const* d_in, const int* in_sizes, int n_in,
                              void* d_out, int out_size, void* d_ws, size_t ws_size,
                              hipStream_t stream) {
    const float* x    = (const float*)d_in[0];
    const float* Wqkv = (const float*)d_in[1];
    const float* bqkv = (const float*)d_in[2];
    const float* Wo   = (const float*)d_in[3];
    const float* bo   = (const float*)d_in[4];
    const float* W1   = (const float*)d_in[5];
    const float* b1   = (const float*)d_in[6];
    const float* W2   = (const float*)d_in[7];
    const float* b2   = (const float*)d_in[8];
    float* out = (float*)d_out;

    const size_t SZ = (size_t)E_ * B_ * H_ * S_ * DH_;  // 8,388,608 elements
    short* qb    = (short*)d_ws;
    short* kb    = qb + SZ;
    short* vtb   = kb + SZ;
    short* ctxbf = vtb + SZ;                 // [E][4096][128] bf16
    short* xbf   = ctxbf + SZ;               // 524288
    short* wbf   = xbf + (size_t)M_ * D_;    // 786432
    short* wobf  = wbf + (size_t)E_ * 3 * D_ * D_;   // 262144
    short* w1bf  = wobf + (size_t)E_ * D_ * D_;      // 131072

    hipFuncSetAttribute((const void*)qkv_mfma_kernel,
                        hipFuncAttributeMaxDynamicSharedMemorySize,
                        QKV_LDS_BYTES);
    hipFuncSetAttribute((const void*)attn_kernel,
                        hipFuncAttributeMaxDynamicSharedMemorySize,
                        ATTN_LDS_BYTES);
    hipFuncSetAttribute((const void*)head_mfma_kernel,
                        hipFuncAttributeMaxDynamicSharedMemorySize,
                        HEAD_LDS_BYTES);

    convert_kernel<<<dim3(832), 256, 0, stream>>>(x, Wqkv, Wo, W1, xbf, wbf, wobf, w1bf);
    qkv_mfma_kernel<<<dim3(3, 32, 16), 512, QKV_LDS_BYTES, stream>>>(xbf, wbf, bqkv, qb, kb, vtb);
    attn_kernel<<<dim3(32, 16), 512, ATTN_LDS_BYTES, stream>>>(qb, kb, vtb, ctxbf);
    head_mfma_kernel<<<dim3(32, 16), 512, HEAD_LDS_BYTES, stream>>>(ctxbf, wobf, bo, w1bf, b1, W2, b2, out);
}

// Round 18
// 74.412 us; speedup vs baseline: 1.0039x; 1.0039x over previous
//
#include <hip/hip_runtime.h>
#include <hip/hip_bf16.h>

// EventSpecificTimingHeads: E=16 per-event attention heads on shared features.
// Round 18: attn VGPR shave targeting 3 blocks/CU (LDS 43.5KB, needs VGPR<=85
// for 24 waves/CU): 2 qf/wave + K-quarter staging (r13 structure) with
// half-batched exp/pack, sequential va loads, unroll-1 kt loop, recomputed
// epilogue addrs. No forced launch bounds (r11 lesson). qkv/head/convert = r17.

#define E_ 16
#define B_ 8
#define S_ 512
#define D_ 128
#define H_ 4
#define DH_ 32
#define H2_ 64
#define M_ (B_ * S_)
// 1/sqrt(32) * log2(e): scores come out of QK^T in log2 domain.
#define QK_SCALE_L2E 0.25503472437616588f

#define HEAD_LDS_BYTES (128 * 136 * 2 * 2)          // 69632
#define QKV_LDS_BYTES  (128 * 136 * 2 * 2)          // 69632 (>= rp 128*132*4)

typedef __attribute__((ext_vector_type(4))) short bf16x4;
typedef __attribute__((ext_vector_type(8))) short bf16x8;
typedef __attribute__((ext_vector_type(4))) float f32x4;

__device__ __forceinline__ short f2bf(float f) {
    unsigned u = __builtin_bit_cast(unsigned, f);
    u += 0x7fffu + ((u >> 16) & 1u);   // RNE
    return (short)(u >> 16);
}

__device__ __forceinline__ unsigned pk2(float lo, float hi) {
    __hip_bfloat162 t = __float22bfloat162_rn(make_float2(lo, hi));
    unsigned r;
    __builtin_memcpy(&r, &t, sizeof(r));
    return r;
}

__device__ __forceinline__ bf16x8 cat8(bf16x4 lo, bf16x4 hi) {
    return __builtin_shufflevector(lo, hi, 0, 1, 2, 3, 4, 5, 6, 7);
}

// ---------------------------------------------------------------------------
// Kernel 0: fp32 -> bf16 convert: x, Wqkv, Wo, W1. (convert once, read many)
// ---------------------------------------------------------------------------
__global__ __launch_bounds__(256) void convert_kernel(
    const float* __restrict__ x, const float* __restrict__ w,
    const float* __restrict__ wo, const float* __restrict__ w1,
    short* __restrict__ xbf, short* __restrict__ wbf,
    short* __restrict__ wobf, short* __restrict__ w1bf)
{
    const int XN  = (M_ * D_) / 8;             // 65536
    const int WN  = (E_ * 3 * D_ * D_) / 8;    // 98304
    const int WON = (E_ * D_ * D_) / 8;        // 32768
    const int W1N = (E_ * H2_ * D_) / 8;       // 16384
    int idx = blockIdx.x * 256 + threadIdx.x;
    const float* src; short* dst; int off;
    if (idx < XN)                        { src = x;  dst = xbf;  off = idx; }
    else if (idx < XN + WN)              { src = w;  dst = wbf;  off = idx - XN; }
    else if (idx < XN + WN + WON)        { src = wo; dst = wobf; off = idx - XN - WN; }
    else if (idx < XN + WN + WON + W1N)  { src = w1; dst = w1bf; off = idx - XN - WN - WON; }
    else return;
    float4 v0 = *(const float4*)&src[(size_t)off * 8];
    float4 v1 = *(const float4*)&src[(size_t)off * 8 + 4];
    bf16x8 o;
    o[0] = f2bf(v0.x); o[1] = f2bf(v0.y); o[2] = f2bf(v0.z); o[3] = f2bf(v0.w);
    o[4] = f2bf(v1.x); o[5] = f2bf(v1.y); o[6] = f2bf(v1.z); o[7] = f2bf(v1.w);
    *(bf16x8*)&dst[(size_t)off * 8] = o;
}

// ---------------------------------------------------------------------------
// Kernel 1: QKV GEMM, 512-thr blocks, 128x128 tiles (unchanged from r17).
// ---------------------------------------------------------------------------
__global__ __launch_bounds__(512) void qkv_mfma_kernel(
    const short* __restrict__ xbf,   // [4096][128] bf16
    const short* __restrict__ wbf,   // [16][384][128] bf16
    const float* __restrict__ bqkv,  // [16][384]
    short* __restrict__ q, short* __restrict__ k, short* __restrict__ v)
{
    extern __shared__ __align__(16) char lds[];
    short (*xs)[136] = (short(*)[136])lds;
    short (*ws)[136] = (short(*)[136])(lds + 128 * 136 * 2);

    const int ct2 = blockIdx.x;  // 0..2
    const int rt  = blockIdx.y;  // 0..31
    const int e   = blockIdx.z;  // 0..15
    const int tid = threadIdx.x;
    const int w    = tid >> 6;
    const int lane = tid & 63;
    const int l15  = lane & 15;
    const int g    = lane >> 4;

    #pragma unroll
    for (int p = 0; p < 4; ++p) {
        int idx = tid + p * 512;
        int row = idx >> 4, c8 = (idx & 15) * 8;
        *(bf16x8*)&xs[row][c8] =
            *(const bf16x8*)&xbf[(size_t)(rt * 128 + row) * 128 + c8];
        *(bf16x8*)&ws[row][c8] =
            *(const bf16x8*)&wbf[((size_t)e * 384 + ct2 * 128 + row) * 128 + c8];
    }
    __syncthreads();

    const int m0 = (w >> 2) * 64;
    const int n0 = (w & 3) * 32;
    f32x4 acc[4][2] = {};

    #pragma unroll
    for (int kk = 0; kk < 128; kk += 32) {
        bf16x8 A0 = cat8(*(const bf16x4*)&ws[n0      + l15][kk + 4 * g],
                         *(const bf16x4*)&ws[n0      + l15][kk + 16 + 4 * g]);
        bf16x8 A1 = cat8(*(const bf16x4*)&ws[n0 + 16 + l15][kk + 4 * g],
                         *(const bf16x4*)&ws[n0 + 16 + l15][kk + 16 + 4 * g]);
        #pragma unroll
        for (int mm = 0; mm < 4; ++mm) {
            bf16x8 Bm = cat8(*(const bf16x4*)&xs[m0 + mm * 16 + l15][kk + 4 * g],
                             *(const bf16x4*)&xs[m0 + mm * 16 + l15][kk + 16 + 4 * g]);
            acc[mm][0] = __builtin_amdgcn_mfma_f32_16x16x32_bf16(A0, Bm, acc[mm][0], 0, 0, 0);
            acc[mm][1] = __builtin_amdgcn_mfma_f32_16x16x32_bf16(A1, Bm, acc[mm][1], 0, 0, 0);
        }
    }

    if (ct2 < 2) {
        short* dst = (ct2 == 0) ? q : k;
        const float scale = (ct2 == 0) ? QK_SCALE_L2E : 1.0f;
        #pragma unroll
        for (int mm = 0; mm < 4; ++mm) {
            #pragma unroll
            for (int nn = 0; nn < 2; ++nn) {
                const int d  = n0 + nn * 16 + 4 * g;
                const int h  = d >> 5, dh = d & 31;
                const int jb = ct2 * 128 + d;
                const float b0 = bqkv[e * 384 + jb + 0];
                const float b1 = bqkv[e * 384 + jb + 1];
                const float b2 = bqkv[e * 384 + jb + 2];
                const float b3 = bqkv[e * 384 + jb + 3];
                const int m  = rt * 128 + m0 + mm * 16 + l15;
                const int bb = m >> 9, s = m & 511;
                bf16x4 o;
                o[0] = f2bf((acc[mm][nn][0] + b0) * scale);
                o[1] = f2bf((acc[mm][nn][1] + b1) * scale);
                o[2] = f2bf((acc[mm][nn][2] + b2) * scale);
                o[3] = f2bf((acc[mm][nn][3] + b3) * scale);
                *(bf16x4*)&dst[((((size_t)e * B_ + bb) * H_ + h) * S_ + s) * DH_ + dh] = o;
            }
        }
    } else {
        __syncthreads();
        float (*rp)[132] = (float(*)[132])lds;
        #pragma unroll
        for (int mm = 0; mm < 4; ++mm) {
            #pragma unroll
            for (int nn = 0; nn < 2; ++nn) {
                const int jl = n0 + nn * 16 + 4 * g;
                const int ml = m0 + mm * 16 + l15;
                rp[jl + 0][ml] = acc[mm][nn][0];
                rp[jl + 1][ml] = acc[mm][nn][1];
                rp[jl + 2][ml] = acc[mm][nn][2];
                rp[jl + 3][ml] = acc[mm][nn][3];
            }
        }
        __syncthreads();
        const int bb = (rt * 128) >> 9;
        const int sb = (rt * 128) & 511;
        #pragma unroll
        for (int p = 0; p < 4; ++p) {
            int task = tid + p * 512;
            int jl = task >> 4, sc = (task & 15) * 8;
            const int h = jl >> 5, dh = jl & 31;
            const float bias = bqkv[e * 384 + 256 + jl];
            bf16x8 o;
            #pragma unroll
            for (int j = 0; j < 8; ++j) o[j] = f2bf(rp[jl][sc + j] + bias);
            *(bf16x8*)&v[((((size_t)e * B_ + bb) * H_ + h) * DH_ + dh) * S_ + sb + sc] = o;
        }
    }
}

// ---------------------------------------------------------------------------
// Kernel 2: flash attention, VGPR-shaved. Grid (qh, bh, e); 8 waves x 32
// q-rows (2 qf/wave). K quarter-staged (10.2KB) + full V^T (33.3KB) = 43.5KB
// static LDS -> 3 blocks/CU IF VGPR <= 85. Half-batched exp/pack, sequential
// va loads, unroll-1 kt loop to minimize live ranges.
// ---------------------------------------------------------------------------
__global__ __launch_bounds__(512) void attn_kernel(
    const short* __restrict__ q, const short* __restrict__ k,
    const short* __restrict__ vt, short* __restrict__ ctxbf)
{
    __shared__ alignas(16) short Ks[128][40];    // quarter of K (10.2 KB)
    __shared__ alignas(16) short VTs[32][520];   // full V^T (33.3 KB)

    const int qh  = blockIdx.x;   // 0..1 (q half)
    const int bh  = blockIdx.y;   // 0..31
    const int e   = blockIdx.z;   // 0..15
    const int tid = threadIdx.x;
    const int w    = tid >> 6;
    const int lane = tid & 63;
    const int l15  = lane & 15;
    const int g    = lane >> 4;

    const size_t base = ((size_t)e * 32 + bh) * (S_ * DH_);
    const short* qg = q  + base;
    const short* kg = k  + base;
    const short* vg = vt + base;

    // ---- stage V^T (full) ----
    {
        int d = tid >> 4, c0 = (tid & 15) * 32;
        const uint4* src = (const uint4*)(vg + (size_t)d * S_ + c0);
        uint4* dst = (uint4*)((char*)&VTs[0][0] + (size_t)d * 1040 + c0 * 2);
        dst[0] = src[0]; dst[1] = src[1]; dst[2] = src[2]; dst[3] = src[3];
    }
    // ---- stage K quarter 0 ----
    {
        int row = tid >> 2, ch = (tid & 3) * 8;
        *(uint4*)((char*)&Ks[0][0] + (size_t)row * 80 + ch * 2) =
            *(const uint4*)(kg + (size_t)row * DH_ + ch);
    }
    // ---- Q fragments: 2 per wave (rows qh*256 + w*32 + qf*16 + l15) ----
    bf16x8 bq0, bq1;
    {
        const short* qp = qg + (size_t)(qh * 256 + w * 32 + l15) * DH_;
        bq0 = cat8(*(const bf16x4*)(qp + 4 * g), *(const bf16x4*)(qp + 16 + 4 * g));
        qp += 16 * DH_;
        bq1 = cat8(*(const bf16x4*)(qp + 4 * g), *(const bf16x4*)(qp + 16 + 4 * g));
    }
    __syncthreads();

    f32x4 acc00 = {0.f,0.f,0.f,0.f}, acc01 = {0.f,0.f,0.f,0.f};
    f32x4 acc10 = {0.f,0.f,0.f,0.f}, acc11 = {0.f,0.f,0.f,0.f};
    float lsum0 = 0.f, lsum1 = 0.f;

    for (int quarter = 0; quarter < 4; ++quarter) {
        #pragma unroll 1
        for (int kt = 0; kt < 4; ++kt) {
            // K fragments for this 32-key step
            const char* kp0 = (const char*)&Ks[0][0] + (size_t)(kt * 32 + l15) * 80 + g * 8;
            bf16x8 ka0 = cat8(*(const bf16x4*)kp0, *(const bf16x4*)(kp0 + 32));
            const char* kp1 = kp0 + 16 * 80;
            bf16x8 ka1 = cat8(*(const bf16x4*)kp1, *(const bf16x4*)(kp1 + 32));

            bf16x8 pf0, pf1;
            // ---- qf = 0: scores + exp in two half-batches ----
            {
                f32x4 z = {0.f, 0.f, 0.f, 0.f};
                f32x4 s0 = __builtin_amdgcn_mfma_f32_16x16x32_bf16(ka0, bq0, z, 0, 0, 0);
                f32x4 s1 = __builtin_amdgcn_mfma_f32_16x16x32_bf16(ka1, bq0, z, 0, 0, 0);
                float p0 = __builtin_amdgcn_exp2f(s0[0]);
                float p1 = __builtin_amdgcn_exp2f(s0[1]);
                float p2 = __builtin_amdgcn_exp2f(s0[2]);
                float p3 = __builtin_amdgcn_exp2f(s0[3]);
                lsum0 += (p0 + p1) + (p2 + p3);
                unsigned u0 = pk2(p0, p1), u1 = pk2(p2, p3);
                p0 = __builtin_amdgcn_exp2f(s1[0]);
                p1 = __builtin_amdgcn_exp2f(s1[1]);
                p2 = __builtin_amdgcn_exp2f(s1[2]);
                p3 = __builtin_amdgcn_exp2f(s1[3]);
                lsum0 += (p0 + p1) + (p2 + p3);
                uint4 uu = make_uint4(u0, u1, pk2(p0, p1), pk2(p2, p3));
                pf0 = __builtin_bit_cast(bf16x8, uu);
            }
            // ---- qf = 1 ----
            {
                f32x4 z = {0.f, 0.f, 0.f, 0.f};
                f32x4 s0 = __builtin_amdgcn_mfma_f32_16x16x32_bf16(ka0, bq1, z, 0, 0, 0);
                f32x4 s1 = __builtin_amdgcn_mfma_f32_16x16x32_bf16(ka1, bq1, z, 0, 0, 0);
                float p0 = __builtin_amdgcn_exp2f(s0[0]);
                float p1 = __builtin_amdgcn_exp2f(s0[1]);
                float p2 = __builtin_amdgcn_exp2f(s0[2]);
                float p3 = __builtin_amdgcn_exp2f(s0[3]);
                lsum1 += (p0 + p1) + (p2 + p3);
                unsigned u0 = pk2(p0, p1), u1 = pk2(p2, p3);
                p0 = __builtin_amdgcn_exp2f(s1[0]);
                p1 = __builtin_amdgcn_exp2f(s1[1]);
                p2 = __builtin_amdgcn_exp2f(s1[2]);
                p3 = __builtin_amdgcn_exp2f(s1[3]);
                lsum1 += (p0 + p1) + (p2 + p3);
                uint4 uu = make_uint4(u0, u1, pk2(p0, p1), pk2(p2, p3));
                pf1 = __builtin_bit_cast(bf16x8, uu);
            }
            // ---- PV: sequential va loads, each consumed by both qf ----
            const int keyb = quarter * 128 + kt * 32;
            const char* vp = (const char*)&VTs[0][0] + (size_t)l15 * 1040 + (keyb + 4 * g) * 2;
            {
                bf16x8 va = cat8(*(const bf16x4*)vp, *(const bf16x4*)(vp + 32));
                acc00 = __builtin_amdgcn_mfma_f32_16x16x32_bf16(va, pf0, acc00, 0, 0, 0);
                acc01 = __builtin_amdgcn_mfma_f32_16x16x32_bf16(va, pf1, acc01, 0, 0, 0);
            }
            {
                const char* vq = vp + 16 * 1040;
                bf16x8 va = cat8(*(const bf16x4*)vq, *(const bf16x4*)(vq + 32));
                acc10 = __builtin_amdgcn_mfma_f32_16x16x32_bf16(va, pf0, acc10, 0, 0, 0);
                acc11 = __builtin_amdgcn_mfma_f32_16x16x32_bf16(va, pf1, acc11, 0, 0, 0);
            }
        }
        if (quarter < 3) {
            __syncthreads();
            int row = tid >> 2, ch = (tid & 3) * 8;
            *(uint4*)((char*)&Ks[0][0] + (size_t)row * 80 + ch * 2) =
                *(const uint4*)(kg + (size_t)((quarter + 1) * 128 + row) * DH_ + ch);
            __syncthreads();
        }
    }

    // ---- denominators + ctx write (bf16 row-major [e][b][s][128]) ----
    {
        float ls = lsum0;
        ls += __shfl_xor(ls, 16);
        ls += __shfl_xor(ls, 32);
        const float inv = 1.0f / ls;
        short* cg = ctxbf + (((size_t)(e * B_ + (bh >> 2)) * S_ + (qh * 256 + w * 32 + l15)) * D_
                             + (bh & 3) * DH_);
        bf16x4 o0, o1;
        #pragma unroll
        for (int r = 0; r < 4; ++r) {
            o0[r] = f2bf(acc00[r] * inv);
            o1[r] = f2bf(acc10[r] * inv);
        }
        *(bf16x4*)&cg[4 * g]      = o0;
        *(bf16x4*)&cg[16 + 4 * g] = o1;
    }
    {
        float ls = lsum1;
        ls += __shfl_xor(ls, 16);
        ls += __shfl_xor(ls, 32);
        const float inv = 1.0f / ls;
        short* cg = ctxbf + (((size_t)(e * B_ + (bh >> 2)) * S_ + (qh * 256 + w * 32 + 16 + l15)) * D_
                             + (bh & 3) * DH_);
        bf16x4 o0, o1;
        #pragma unroll
        for (int r = 0; r < 4; ++r) {
            o0[r] = f2bf(acc01[r] * inv);
            o1[r] = f2bf(acc11[r] * inv);
        }
        *(bf16x4*)&cg[4 * g]      = o0;
        *(bf16x4*)&cg[16 + 4 * g] = o1;
    }
}

// ---------------------------------------------------------------------------
// Kernel 3: head, 512-thr blocks, 128 rows (unchanged from r16/r17).
// ---------------------------------------------------------------------------
__global__ __launch_bounds__(512) void head_mfma_kernel(
    const short* __restrict__ ctxbf,  // [E][4096][128] bf16
    const short* __restrict__ wobf,   // [E][128][128] bf16
    const float* __restrict__ bo,     // [E][128]
    const short* __restrict__ w1bf,   // [E][64][128] bf16
    const float* __restrict__ b1,     // [E][64]
    const float* __restrict__ W2,     // [E][64]
    const float* __restrict__ b2,     // [E]
    float* __restrict__ out)          // [B][S][E]
{
    extern __shared__ __align__(16) char smem[];
    short (*Wos)[136] = (short(*)[136])smem;
    short (*cts)[136] = (short(*)[136])(smem + 128 * 136 * 2);

    const int mt  = blockIdx.x;   // 0..31
    const int e   = blockIdx.y;
    const int tid = threadIdx.x;
    const int w    = tid >> 6;
    const int lane = tid & 63;
    const int l15  = lane & 15;
    const int g    = lane >> 4;

    #pragma unroll
    for (int p = 0; p < 4; ++p) {
        int idx = tid + p * 512;
        int row = idx >> 4, c8 = (idx & 15) * 8;
        *(bf16x8*)&Wos[row][c8] =
            *(const bf16x8*)&wobf[((size_t)e * 128 + row) * 128 + c8];
        *(bf16x8*)&cts[row][c8] =
            *(const bf16x8*)&ctxbf[((size_t)e * M_ + mt * 128 + row) * 128 + c8];
    }
    __syncthreads();

    f32x4 accA[8] = {};
    #pragma unroll
    for (int kk = 0; kk < 128; kk += 32) {
        bf16x8 a = cat8(*(const bf16x4*)&cts[w * 16 + l15][kk + 4 * g],
                        *(const bf16x4*)&cts[w * 16 + l15][kk + 16 + 4 * g]);
        #pragma unroll
        for (int t = 0; t < 8; ++t) {
            bf16x8 bfr = cat8(*(const bf16x4*)&Wos[t * 16 + l15][kk + 4 * g],
                              *(const bf16x4*)&Wos[t * 16 + l15][kk + 16 + 4 * g]);
            accA[t] = __builtin_amdgcn_mfma_f32_16x16x32_bf16(a, bfr, accA[t], 0, 0, 0);
        }
    }
    __syncthreads();

    #pragma unroll
    for (int p = 0; p < 2; ++p) {
        int idx = tid + p * 512;
        int row = idx >> 4, c8 = (idx & 15) * 8;
        *(bf16x8*)&Wos[row][c8] =
            *(const bf16x8*)&w1bf[((size_t)e * 64 + row) * 128 + c8];
    }
    #pragma unroll
    for (int t = 0; t < 8; ++t) {
        const float bov = bo[e * 128 + t * 16 + l15];
        #pragma unroll
        for (int r = 0; r < 4; ++r)
            cts[w * 16 + 4 * g + r][t * 16 + l15] = f2bf(accA[t][r] + bov);
    }
    __syncthreads();

    f32x4 accB[4] = {};
    #pragma unroll
    for (int kk = 0; kk < 128; kk += 32) {
        bf16x8 a = cat8(*(const bf16x4*)&cts[w * 16 + l15][kk + 4 * g],
                        *(const bf16x4*)&cts[w * 16 + l15][kk + 16 + 4 * g]);
        #pragma unroll
        for (int t = 0; t < 4; ++t) {
            bf16x8 bfr = cat8(*(const bf16x4*)&Wos[t * 16 + l15][kk + 4 * g],
                              *(const bf16x4*)&Wos[t * 16 + l15][kk + 16 + 4 * g]);
            accB[t] = __builtin_amdgcn_mfma_f32_16x16x32_bf16(a, bfr, accB[t], 0, 0, 0);
        }
    }

    float b1v[4], w2v[4];
    #pragma unroll
    for (int t = 0; t < 4; ++t) {
        b1v[t] = b1[e * 64 + t * 16 + l15];
        w2v[t] = W2[e * 64 + t * 16 + l15];
    }
    const float b2v = b2[e];
    #pragma unroll
    for (int r = 0; r < 4; ++r) {
        float s = 0.f;
        #pragma unroll
        for (int t = 0; t < 4; ++t)
            s += fmaxf(accB[t][r] + b1v[t], 0.f) * w2v[t];
        s += __shfl_xor(s, 1);
        s += __shfl_xor(s, 2);
        s += __shfl_xor(s, 4);
        s += __shfl_xor(s, 8);
        if (l15 == 0) {
            const int m = mt * 128 + w * 16 + 4 * g + r;
            const int bb = m >> 9, ss = m & 511;
            out[((size_t)(bb * S_ + ss)) * E_ + e] = s + b2v;
        }
    }
}

// ---------------------------------------------------------------------------
extern "C" void kernel_launch(void* const* d_in, const int* in_sizes, int n_in,
                              void* d_out, int out_size, void* d_ws, size_t ws_size,
                              hipStream_t stream) {
    const float* x    = (const float*)d_in[0];
    const float* Wqkv = (const float*)d_in[1];
    const float* bqkv = (const float*)d_in[2];
    const float* Wo   = (const float*)d_in[3];
    const float* bo   = (const float*)d_in[4];
    const float* W1   = (const float*)d_in[5];
    const float* b1   = (const float*)d_in[6];
    const float* W2   = (const float*)d_in[7];
    const float* b2   = (const float*)d_in[8];
    float* out = (float*)d_out;

    const size_t SZ = (size_t)E_ * B_ * H_ * S_ * DH_;  // 8,388,608 elements
    short* qb    = (short*)d_ws;
    short* kb    = qb + SZ;
    short* vtb   = kb + SZ;
    short* ctxbf = vtb + SZ;                 // [E][4096][128] bf16
    short* xbf   = ctxbf + SZ;               // 524288
    short* wbf   = xbf + (size_t)M_ * D_;    // 786432
    short* wobf  = wbf + (size_t)E_ * 3 * D_ * D_;   // 262144
    short* w1bf  = wobf + (size_t)E_ * D_ * D_;      // 131072

    hipFuncSetAttribute((const void*)qkv_mfma_kernel,
                        hipFuncAttributeMaxDynamicSharedMemorySize,
                        QKV_LDS_BYTES);
    hipFuncSetAttribute((const void*)head_mfma_kernel,
                        hipFuncAttributeMaxDynamicSharedMemorySize,
                        HEAD_LDS_BYTES);

    convert_kernel<<<dim3(832), 256, 0, stream>>>(x, Wqkv, Wo, W1, xbf, wbf, wobf, w1bf);
    qkv_mfma_kernel<<<dim3(3, 32, 16), 512, QKV_LDS_BYTES, stream>>>(xbf, wbf, bqkv, qb, kb, vtb);
    attn_kernel<<<dim3(2, 32, 16), 512, 0, stream>>>(qb, kb, vtb, ctxbf);
    head_mfma_kernel<<<dim3(32, 16), 512, HEAD_LDS_BYTES, stream>>>(ctxbf, wobf, bo, w1bf, b1, W2, b2, out);
}